// Round 5
// baseline (1332.508 us; speedup 1.0000x reference)
//
#include <hip/hip_runtime.h>
#include <hip/hip_bf16.h>
#include <stdint.h>

typedef unsigned short ushort_t;
typedef unsigned int uint_t;

// Problem sizes (fixed by reference)
#define BB 16
#define TT 2048
#define DD 1024
#define HH 1024
#define MM (BB * TT)   // 32768
#define NN (3 * HH)    // 3072
#define KK DD          // 1024
#define NCHUNK 128
#define CLEN (TT / NCHUNK)  // 16

typedef __bf16 bf16x8 __attribute__((ext_vector_type(8)));
typedef float floatx4 __attribute__((ext_vector_type(4)));

// ---------- helpers ----------
__device__ __forceinline__ ushort_t f2b(float f) {
  union { float f; uint_t u; } v; v.f = f;
  uint_t u = v.u;
  uint_t r = (u + 0x7FFFu + ((u >> 16) & 1u)) >> 16;  // RNE
  return (ushort_t)r;
}
__device__ __forceinline__ float b2f_lo(uint_t u) {
  union { uint_t u; float f; } v; v.u = u << 16; return v.f;
}
__device__ __forceinline__ float b2f_hi(uint_t u) {
  union { uint_t u; float f; } v; v.u = u & 0xFFFF0000u; return v.f;
}
__device__ __forceinline__ float fast_sigmoid(float x) {
  return 1.0f / (1.0f + __expf(-x));
}
__device__ __forceinline__ float fast_tanh(float x) {
  x = fminf(fmaxf(x, -15.0f), 15.0f);
  float e = __expf(2.0f * x);
  return (e - 1.0f) / (e + 1.0f);
}

// async global->LDS, 16B per lane, dst = wave-uniform base + lane*16
__device__ __forceinline__ void async_ld16(const void* g, void* l) {
  auto gp = (const __attribute__((address_space(1))) unsigned int*)(uintptr_t)g;
  unsigned loff = (unsigned)(uintptr_t)l;  // generic LDS ptr low 32 bits = LDS addr
  auto lp = (__attribute__((address_space(3))) unsigned int*)loff;
  __builtin_amdgcn_global_load_lds(gp, lp, 16, 0, 0);
}

// device-scope grid barrier (G16 protocol). Safe iff all blocks co-resident.
__device__ __forceinline__ void grid_barrier(uint_t* cnt, uint_t target) {
  __threadfence();          // release: drain this block's writes (agent scope)
  __syncthreads();
  if (threadIdx.x == 0) {
    __hip_atomic_fetch_add(cnt, 1u, __ATOMIC_ACQ_REL, __HIP_MEMORY_SCOPE_AGENT);
    while (__hip_atomic_load(cnt, __ATOMIC_ACQUIRE, __HIP_MEMORY_SCOPE_AGENT) < target) {
      __builtin_amdgcn_s_sleep(8);
    }
  }
  __syncthreads();
  __threadfence();          // acquire: invalidate stale lines before reading
}

// ---------- kernel 1: fused prep = cvt_x (blocks 0..2047) + transW (blocks 2048..5119)
__global__ __launch_bounds__(256) void prep_kernel(const float4* __restrict__ x,
                                                   uint4* __restrict__ xbf,
                                                   const float* __restrict__ W,
                                                   ushort_t* __restrict__ Wt,
                                                   uint_t* __restrict__ counters) {
  __shared__ ushort_t tile[32][33];
  const int bid = blockIdx.x;
  const int tid = threadIdx.x;
  if (bid == 0 && tid < 2) counters[tid] = 0;  // reset scan barrier counters (each replay)
  if (bid < 2048) {
    const int n8 = MM * KK / 8;
    const int stride = 2048 * 256;
    for (int i = bid * 256 + tid; i < n8; i += stride) {
      float4 a = x[2 * i], b = x[2 * i + 1];
      uint4 r;
      r.x = (uint_t)f2b(a.x) | ((uint_t)f2b(a.y) << 16);
      r.y = (uint_t)f2b(a.z) | ((uint_t)f2b(a.w) << 16);
      r.z = (uint_t)f2b(b.x) | ((uint_t)f2b(b.y) << 16);
      r.w = (uint_t)f2b(b.z) | ((uint_t)f2b(b.w) << 16);
      xbf[i] = r;
    }
  } else {
    const int b2 = bid - 2048;       // 0..3071
    const int bx = b2 % (NN / 32);   // n-tile
    const int by = b2 / (NN / 32);   // k-tile
    const int tx = tid & 31;
    const int ty = tid >> 5;
    const int n0 = bx * 32;
    const int k0 = by * 32;
#pragma unroll
    for (int r = 0; r < 4; r++) {
      int k = k0 + ty + r * 8;
      tile[ty + r * 8][tx] = f2b(W[(size_t)k * NN + n0 + tx]);
    }
    __syncthreads();
#pragma unroll
    for (int r = 0; r < 4; r++) {
      int n = n0 + ty + r * 8;
      Wt[(size_t)n * KK + k0 + tx] = tile[tx][ty + r * 8];
    }
  }
}

// ---------- kernel 2: 8-phase 256x256 GEMM (T1+T2+T3+T4+T5) ----------
// K-loop identical to round-1 (race-verified). LDS-staged coalesced epilogue (round-2).
#define GBM 256
#define GBN 256
#define GBK 64
#define GNT (KK / GBK)        // 16 K-tiles
#define NWG_M (MM / GBM)      // 128
#define NWG_N (NN / GBN)      // 12
#define NWG (NWG_M * NWG_N)   // 1536

__global__ __launch_bounds__(512, 2) void gemm8_kernel(const ushort_t* __restrict__ Abf,
                                                       const ushort_t* __restrict__ Btb,
                                                       const float* __restrict__ bias,
                                                       ushort_t* __restrict__ U) {
  extern __shared__ char smem[];  // 131072 B: A at [0,65536), B at [65536,131072)
  const int tid = threadIdx.x;
  const int lane = tid & 63;
  const int w = tid >> 6;       // wave 0..7
  const int wm = w >> 2;        // 0..1
  const int wn = w & 3;         // 0..3

  // T1: bijective XCD swizzle (NWG % 8 == 0), bn fastest within an XCD chunk
  const int wg = blockIdx.x;
  const int nid = (wg & 7) * (NWG / 8) + (wg >> 3);
  const int bm = nid / NWG_N;
  const int bn = nid - bm * NWG_N;
  const int rowA0 = bm * GBM;
  const int rowB0 = bn * GBN;

  // ---- staging addressing (inverse-swizzled global source, linear LDS dest) ----
  const int r128 = tid >> 2;                       // 0..127
  const int qsw = (tid & 3) ^ ((r128 >> 1) & 3);   // same for row r128+128
  const ushort_t* gA1 = Abf + (size_t)(rowA0 + r128) * KK + qsw * 8;
  const ushort_t* gA2 = gA1 + (size_t)128 * KK;
  const ushort_t* gB1 = Btb + (size_t)(rowB0 + r128) * KK + qsw * 8;
  const ushort_t* gB2 = gB1 + (size_t)128 * KK;
  char* const sA = smem;
  char* const sB = smem + 65536;
  const int woff = w * 1024;    // wave-uniform dest base within region

  // ---- read addressing (swizzled ds_read) ----
  const int m16 = lane & 15;
  const int q = lane >> 4;                    // K-quad (8 bf16)
  const int rsw = (q ^ ((m16 >> 1) & 3)) * 16;
  const int aoff = (wm * 128 + m16) * 64 + rsw;   // + i*1024 per m-frag
  const int boff = (wn * 64 + m16) * 64 + rsw;    // + j*1024 per n-frag

  floatx4 acc[8][4];
#pragma unroll
  for (int i = 0; i < 8; i++)
#pragma unroll
    for (int j = 0; j < 4; j++) acc[i][j] = (floatx4){0.f, 0.f, 0.f, 0.f};

  bf16x8 bfrag[4];  // B frags persist across the two m-half phases of a K-half

#define STAGE_A(kt_, par_, kh_)                                          \
  do {                                                                   \
    const int ko_ = (kt_) * GBK + (kh_) * 32;                            \
    char* d_ = sA + ((par_) * 32768 + (kh_) * 16384) + woff;             \
    async_ld16(gA1 + ko_, d_);                                           \
    async_ld16(gA2 + ko_, d_ + 8192);                                    \
  } while (0)
#define STAGE_B(kt_, par_, kh_)                                          \
  do {                                                                   \
    const int ko_ = (kt_) * GBK + (kh_) * 32;                            \
    char* d_ = sB + ((par_) * 32768 + (kh_) * 16384) + woff;             \
    async_ld16(gB1 + ko_, d_);                                           \
    async_ld16(gB2 + ko_, d_ + 8192);                                    \
  } while (0)

#define VM6 asm volatile("s_waitcnt vmcnt(6)" ::: "memory")
#define VM0 asm volatile("s_waitcnt vmcnt(0)" ::: "memory")

#define PHASE(p_, kh_, mh_, STAGES, VMW)                                          \
  do {                                                                            \
    const char* ab_ = sA + ((p_) * 32768 + (kh_) * 16384) + aoff;                 \
    bf16x8 af_[4];                                                                \
    _Pragma("unroll") for (int i_ = 0; i_ < 4; i_++)                              \
        af_[i_] = *(const bf16x8*)(ab_ + ((mh_) * 4 + i_) * 1024);                \
    if ((mh_) == 0) {                                                             \
      const char* bb_ = sB + ((p_) * 32768 + (kh_) * 16384) + boff;               \
      _Pragma("unroll") for (int j_ = 0; j_ < 4; j_++)                            \
          bfrag[j_] = *(const bf16x8*)(bb_ + j_ * 1024);                          \
    }                                                                             \
    STAGES;                                                                       \
    __builtin_amdgcn_sched_barrier(0);                                            \
    __builtin_amdgcn_s_barrier();                                                 \
    __builtin_amdgcn_sched_barrier(0);                                            \
    asm volatile("s_waitcnt lgkmcnt(0)" ::: "memory");                            \
    __builtin_amdgcn_sched_barrier(0);                                            \
    __builtin_amdgcn_s_setprio(1);                                                \
    _Pragma("unroll") for (int i_ = 0; i_ < 4; i_++) {                            \
      _Pragma("unroll") for (int j_ = 0; j_ < 4; j_++) {                          \
        acc[(mh_) * 4 + i_][j_] = __builtin_amdgcn_mfma_f32_16x16x32_bf16(        \
            af_[i_], bfrag[j_], acc[(mh_) * 4 + i_][j_], 0, 0, 0);                \
      }                                                                           \
    }                                                                             \
    __builtin_amdgcn_s_setprio(0);                                                \
    VMW;                                                                          \
    __builtin_amdgcn_sched_barrier(0);                                            \
    __builtin_amdgcn_s_barrier();                                                 \
    __builtin_amdgcn_sched_barrier(0);                                            \
  } while (0)

  // ---- prologue ----
  STAGE_A(0, 0, 0); STAGE_B(0, 0, 0); STAGE_A(0, 0, 1); STAGE_B(0, 0, 1);
  STAGE_B(1, 1, 0); STAGE_A(1, 1, 0); STAGE_B(1, 1, 1);
  VM6;
  __builtin_amdgcn_s_barrier();

  // ---- main loop ----
  for (int it = 0; it < 7; ++it) {
    const int kt0 = 2 * it;
    const int kt1 = 2 * it + 1;
    PHASE(0, 0, 0, STAGE_A(kt0 + 1, 1, 1), );
    PHASE(0, 0, 1, STAGE_B(kt0 + 2, 0, 0), );
    PHASE(0, 1, 0, STAGE_A(kt0 + 2, 0, 0), );
    PHASE(0, 1, 1, STAGE_B(kt0 + 2, 0, 1), VM6);
    PHASE(1, 0, 0, STAGE_A(kt1 + 1, 0, 1), );
    PHASE(1, 0, 1, STAGE_B(kt1 + 2, 1, 0), );
    PHASE(1, 1, 0, STAGE_A(kt1 + 2, 1, 0), );
    PHASE(1, 1, 1, STAGE_B(kt1 + 2, 1, 1), VM6);
  }

  // ---- tail ----
  PHASE(0, 0, 0, STAGE_A(15, 1, 1), );
  PHASE(0, 0, 1, , );
  PHASE(0, 1, 0, , );
  PHASE(0, 1, 1, , VM0);
  PHASE(1, 0, 0, , );
  PHASE(1, 0, 1, , );
  PHASE(1, 1, 0, , );
  PHASE(1, 1, 1, , );

#undef PHASE
#undef STAGE_A
#undef STAGE_B
#undef VM6
#undef VM0

  // ---- epilogue: LDS-staged, coalesced 64B-sector stores ----
  const int mode = bn >> 2;  // 0: x_tilde, 1: f, 2: r
  ushort_t* const eps = (ushort_t*)smem;
  const int EPS = 264;  // ushorts per staged row (528 B): 2-way bank spread
  float bias_r[4];
#pragma unroll
  for (int j = 0; j < 4; j++) bias_r[j] = bias[rowB0 + wn * 64 + j * 16 + m16];

  const int erow = tid >> 2;        // 0..127 read-out row
  const int et3 = tid & 3;          // 16B sub-slot
#pragma unroll
  for (int mh = 0; mh < 2; mh++) {
    __syncthreads();
    if (wm == mh) {
#pragma unroll
      for (int i = 0; i < 8; i++) {
#pragma unroll
        for (int j = 0; j < 4; j++) {
          const int lc = wn * 64 + j * 16 + m16;
#pragma unroll
          for (int r = 0; r < 4; r++) {
            float v = acc[i][j][r] + bias_r[j];
            if (mode != 0) v = fast_sigmoid(v);
            const int lr = i * 16 + q * 4 + r;  // 0..127
            eps[lr * EPS + lc] = f2b(v);
          }
        }
      }
    }
    __syncthreads();
    ushort_t* gout = U + (size_t)(rowA0 + mh * 128 + erow) * NN + rowB0;
#pragma unroll
    for (int k = 0; k < 8; k++) {
      *(uint4*)(gout + k * 32 + et3 * 8) =
          *(const uint4*)(eps + erow * EPS + k * 32 + et3 * 8);
    }
  }
}

// ---------- kernel 3: merged scan = pass1 + fixup + pass3 (grid barriers) ----------
// 1024 blocks x 256 threads; __launch_bounds__(256,4) caps VGPR at 128 ->
// >=4 blocks/CU co-resident x 256 CU = 1024 >= grid  => spin barrier cannot deadlock.
__global__ __launch_bounds__(256, 4) void scan_kernel(const ushort_t* __restrict__ U,
                                                      float* __restrict__ Asum,
                                                      float* __restrict__ Bsum,
                                                      float* __restrict__ Cinit,
                                                      float* __restrict__ out,
                                                      uint_t* __restrict__ counters) {
  const uint_t nblk = gridDim.x;
  const int gid = blockIdx.x * 256 + threadIdx.x;  // 262144
  const int hp = gid & 127;            // 8-col group
  const int chunk = (gid >> 7) & 127;  // 0..127
  const int b = gid >> 14;
  const int row0 = b * TT + chunk * CLEN;
  const ushort_t* base = U + (size_t)row0 * NN + hp * 8;

  // ---- phase A: per-chunk summaries (A = prod f, B = local c end) ----
  {
    float c[8], A[8];
#pragma unroll
    for (int e = 0; e < 8; e++) { c[e] = 0.f; A[e] = 1.f; }
#pragma unroll 4
    for (int t = 0; t < CLEN; t++) {
      const ushort_t* p = base + (size_t)t * NN;
      uint4 xx = *(const uint4*)(p);
      uint4 ff = *(const uint4*)(p + HH);
      float xv[8], fv[8];
      xv[0] = b2f_lo(xx.x); xv[1] = b2f_hi(xx.x);
      xv[2] = b2f_lo(xx.y); xv[3] = b2f_hi(xx.y);
      xv[4] = b2f_lo(xx.z); xv[5] = b2f_hi(xx.z);
      xv[6] = b2f_lo(xx.w); xv[7] = b2f_hi(xx.w);
      fv[0] = b2f_lo(ff.x); fv[1] = b2f_hi(ff.x);
      fv[2] = b2f_lo(ff.y); fv[3] = b2f_hi(ff.y);
      fv[4] = b2f_lo(ff.z); fv[5] = b2f_hi(ff.z);
      fv[6] = b2f_lo(ff.w); fv[7] = b2f_hi(ff.w);
#pragma unroll
      for (int e = 0; e < 8; e++) {
        A[e] *= fv[e];
        c[e] = fv[e] * c[e] + (1.f - fv[e]) * xv[e];
      }
    }
    int sidx = (b * NCHUNK + chunk) * HH + hp * 8;
    float4* A4 = (float4*)(Asum + sidx);
    float4* B4 = (float4*)(Bsum + sidx);
    A4[0] = make_float4(A[0], A[1], A[2], A[3]);
    A4[1] = make_float4(A[4], A[5], A[6], A[7]);
    B4[0] = make_float4(c[0], c[1], c[2], c[3]);
    B4[1] = make_float4(c[4], c[5], c[6], c[7]);
  }

  grid_barrier(&counters[0], nblk);

  // ---- phase B: sequential combine (first 16 blocks; others pass through) ----
  if (gid < 4096) {
    int h4 = gid & 255;   // float4 index within 1024 cols
    int b2 = gid >> 8;
    float4 c = make_float4(0.f, 0.f, 0.f, 0.f);
    const float4* A4 = (const float4*)Asum;
    const float4* B4 = (const float4*)Bsum;
    float4* C4 = (float4*)Cinit;
#pragma unroll 8
    for (int j = 0; j < NCHUNK; j++) {
      int idx = (b2 * NCHUNK + j) * (HH / 4) + h4;
      C4[idx] = c;
      float4 a = A4[idx], bb = B4[idx];
      c.x = bb.x + a.x * c.x;
      c.y = bb.y + a.y * c.y;
      c.z = bb.z + a.z * c.z;
      c.w = bb.w + a.w * c.w;
    }
  }

  grid_barrier(&counters[1], nblk);

  // ---- phase C: final scan producing h ----
  {
    int ci = (b * NCHUNK + chunk) * HH + hp * 8;
    float c[8];
    {
      float4 c0 = *(const float4*)(Cinit + ci);
      float4 c1 = *(const float4*)(Cinit + ci + 4);
      c[0] = c0.x; c[1] = c0.y; c[2] = c0.z; c[3] = c0.w;
      c[4] = c1.x; c[5] = c1.y; c[6] = c1.z; c[7] = c1.w;
    }
    float* obase = out + (size_t)row0 * HH + hp * 8;
#pragma unroll 2
    for (int t = 0; t < CLEN; t++) {
      const ushort_t* p = base + (size_t)t * NN;
      uint4 xx = *(const uint4*)(p);
      uint4 ff = *(const uint4*)(p + HH);
      uint4 rr = *(const uint4*)(p + 2 * HH);
      float xv[8], fv[8], rv[8];
      xv[0] = b2f_lo(xx.x); xv[1] = b2f_hi(xx.x);
      xv[2] = b2f_lo(xx.y); xv[3] = b2f_hi(xx.y);
      xv[4] = b2f_lo(xx.z); xv[5] = b2f_hi(xx.z);
      xv[6] = b2f_lo(xx.w); xv[7] = b2f_hi(xx.w);
      fv[0] = b2f_lo(ff.x); fv[1] = b2f_hi(ff.x);
      fv[2] = b2f_lo(ff.y); fv[3] = b2f_hi(ff.y);
      fv[4] = b2f_lo(ff.z); fv[5] = b2f_hi(ff.z);
      fv[6] = b2f_lo(ff.w); fv[7] = b2f_hi(ff.w);
      rv[0] = b2f_lo(rr.x); rv[1] = b2f_hi(rr.x);
      rv[2] = b2f_lo(rr.y); rv[3] = b2f_hi(rr.y);
      rv[4] = b2f_lo(rr.z); rv[5] = b2f_hi(rr.z);
      rv[6] = b2f_lo(rr.w); rv[7] = b2f_hi(rr.w);
      float h[8];
#pragma unroll
      for (int e = 0; e < 8; e++) {
        c[e] = fv[e] * c[e] + (1.f - fv[e]) * xv[e];
        h[e] = rv[e] * fast_tanh(c[e]) + (1.f - rv[e]) * xv[e];
      }
      float* o = obase + (size_t)t * HH;
      floatx4 h0 = {h[0], h[1], h[2], h[3]};
      floatx4 h1 = {h[4], h[5], h[6], h[7]};
      __builtin_nontemporal_store(h0, (floatx4*)o);
      __builtin_nontemporal_store(h1, (floatx4*)o + 1);
    }
  }
}

extern "C" void kernel_launch(void* const* d_in, const int* in_sizes, int n_in,
                              void* d_out, int out_size, void* d_ws, size_t ws_size,
                              hipStream_t stream) {
  (void)in_sizes; (void)n_in; (void)out_size; (void)ws_size;
  const float* x = (const float*)d_in[0];
  const float* W = (const float*)d_in[1];
  const float* bias = (const float*)d_in[2];
  float* out = (float*)d_out;
  char* ws = (char*)d_ws;

  // workspace layout (~275 MB).
  // Asum/Bsum/Cinit (8 MB each) OVERLAP x_bf (dead after gemm8; stream-ordered).
  ushort_t* x_bf = (ushort_t*)ws;                                     // 67,108,864 B
  ushort_t* Wt   = (ushort_t*)(ws + 67108864ull);                     //  6,291,456 B
  ushort_t* U    = (ushort_t*)(ws + 67108864ull + 6291456ull);        // 201,326,592 B
  float* Asum  = (float*)ws;                                          //  8,388,608 B
  float* Bsum  = (float*)(ws + 8388608ull);                           //  8,388,608 B
  float* Cinit = (float*)(ws + 16777216ull);                          //  8,388,608 B
  uint_t* counters = (uint_t*)(ws + 274726912ull);                    //  8 B

  static int gemm_attr_set = 0;
  if (!gemm_attr_set) {
    (void)hipFuncSetAttribute(reinterpret_cast<const void*>(gemm8_kernel),
                              hipFuncAttributeMaxDynamicSharedMemorySize, 131072);
    gemm_attr_set = 1;
  }

  prep_kernel<<<5120, 256, 0, stream>>>((const float4*)x, (uint4*)x_bf, W, Wt, counters);
  gemm8_kernel<<<NWG, 512, 131072, stream>>>(x_bf, Wt, bias, U);
  scan_kernel<<<1024, 256, 0, stream>>>(U, Asum, Bsum, Cinit, out, counters);
}

// Round 6
// 561.784 us; speedup vs baseline: 2.3719x; 2.3719x over previous
//
#include <hip/hip_runtime.h>
#include <hip/hip_bf16.h>
#include <stdint.h>

typedef unsigned short ushort_t;
typedef unsigned int uint_t;

// Problem sizes (fixed by reference)
#define BB 16
#define TT 2048
#define DD 1024
#define HH 1024
#define MM (BB * TT)   // 32768
#define NN (3 * HH)    // 3072
#define KK DD          // 1024
#define NCHUNK 128
#define CLEN (TT / NCHUNK)  // 16

typedef __bf16 bf16x8 __attribute__((ext_vector_type(8)));
typedef float floatx4 __attribute__((ext_vector_type(4)));
typedef uint_t uintx4 __attribute__((ext_vector_type(4)));

// ---------- helpers ----------
__device__ __forceinline__ ushort_t f2b(float f) {
  union { float f; uint_t u; } v; v.f = f;
  uint_t u = v.u;
  uint_t r = (u + 0x7FFFu + ((u >> 16) & 1u)) >> 16;  // RNE
  return (ushort_t)r;
}
__device__ __forceinline__ float b2f_lo(uint_t u) {
  union { uint_t u; float f; } v; v.u = u << 16; return v.f;
}
__device__ __forceinline__ float b2f_hi(uint_t u) {
  union { uint_t u; float f; } v; v.u = u & 0xFFFF0000u; return v.f;
}
__device__ __forceinline__ float fast_sigmoid(float x) {
  return 1.0f / (1.0f + __expf(-x));
}
__device__ __forceinline__ float fast_tanh(float x) {
  x = fminf(fmaxf(x, -15.0f), 15.0f);
  float e = __expf(2.0f * x);
  return (e - 1.0f) / (e + 1.0f);
}

// async global->LDS, 16B per lane, dst = wave-uniform base + lane*16
__device__ __forceinline__ void async_ld16(const void* g, void* l) {
  auto gp = (const __attribute__((address_space(1))) unsigned int*)(uintptr_t)g;
  unsigned loff = (unsigned)(uintptr_t)l;  // generic LDS ptr low 32 bits = LDS addr
  auto lp = (__attribute__((address_space(3))) unsigned int*)loff;
  __builtin_amdgcn_global_load_lds(gp, lp, 16, 0, 0);
}

// ---------- kernel 1: fused prep = cvt_x (blocks 0..4095) + transW (4096..7167) ----
__global__ __launch_bounds__(256) void prep_kernel(const floatx4* __restrict__ x,
                                                   uintx4* __restrict__ xbf,
                                                   const float* __restrict__ W,
                                                   ushort_t* __restrict__ Wt) {
  __shared__ ushort_t tile[32][33];
  const int bid = blockIdx.x;
  const int tid = threadIdx.x;
  if (bid < 4096) {
    const int n8 = MM * KK / 8;
    const int stride = 4096 * 256;
    for (int i = bid * 256 + tid; i < n8; i += stride) {
      // x is read-once: non-temporal loads keep L3 for x_bf/U
      floatx4 a = __builtin_nontemporal_load(x + 2 * i);
      floatx4 b = __builtin_nontemporal_load(x + 2 * i + 1);
      uintx4 r;
      r.x = (uint_t)f2b(a[0]) | ((uint_t)f2b(a[1]) << 16);
      r.y = (uint_t)f2b(a[2]) | ((uint_t)f2b(a[3]) << 16);
      r.z = (uint_t)f2b(b[0]) | ((uint_t)f2b(b[1]) << 16);
      r.w = (uint_t)f2b(b[2]) | ((uint_t)f2b(b[3]) << 16);
      xbf[i] = r;
    }
  } else {
    const int b2 = bid - 4096;       // 0..3071
    const int bx = b2 % (NN / 32);   // n-tile
    const int by = b2 / (NN / 32);   // k-tile
    const int tx = tid & 31;
    const int ty = tid >> 5;
    const int n0 = bx * 32;
    const int k0 = by * 32;
#pragma unroll
    for (int r = 0; r < 4; r++) {
      int k = k0 + ty + r * 8;
      tile[ty + r * 8][tx] = f2b(W[(size_t)k * NN + n0 + tx]);
    }
    __syncthreads();
#pragma unroll
    for (int r = 0; r < 4; r++) {
      int n = n0 + ty + r * 8;
      Wt[(size_t)n * KK + k0 + tx] = tile[tx][ty + r * 8];
    }
  }
}

// ---------- kernel 2: 8-phase 256x256 GEMM (T1+T2+T3+T4+T5) ----------
// K-loop identical to round-1 (race-verified). LDS-staged coalesced epilogue (round-2).
#define GBM 256
#define GBN 256
#define GBK 64
#define GNT (KK / GBK)        // 16 K-tiles
#define NWG_M (MM / GBM)      // 128
#define NWG_N (NN / GBN)      // 12
#define NWG (NWG_M * NWG_N)   // 1536

__global__ __launch_bounds__(512, 2) void gemm8_kernel(const ushort_t* __restrict__ Abf,
                                                       const ushort_t* __restrict__ Btb,
                                                       const float* __restrict__ bias,
                                                       ushort_t* __restrict__ U) {
  extern __shared__ char smem[];  // 131072 B: A at [0,65536), B at [65536,131072)
  const int tid = threadIdx.x;
  const int lane = tid & 63;
  const int w = tid >> 6;       // wave 0..7
  const int wm = w >> 2;        // 0..1
  const int wn = w & 3;         // 0..3

  // T1: bijective XCD swizzle (NWG % 8 == 0), bn fastest within an XCD chunk
  const int wg = blockIdx.x;
  const int nid = (wg & 7) * (NWG / 8) + (wg >> 3);
  const int bm = nid / NWG_N;
  const int bn = nid - bm * NWG_N;
  const int rowA0 = bm * GBM;
  const int rowB0 = bn * GBN;

  // ---- staging addressing (inverse-swizzled global source, linear LDS dest) ----
  const int r128 = tid >> 2;                       // 0..127
  const int qsw = (tid & 3) ^ ((r128 >> 1) & 3);   // same for row r128+128
  const ushort_t* gA1 = Abf + (size_t)(rowA0 + r128) * KK + qsw * 8;
  const ushort_t* gA2 = gA1 + (size_t)128 * KK;
  const ushort_t* gB1 = Btb + (size_t)(rowB0 + r128) * KK + qsw * 8;
  const ushort_t* gB2 = gB1 + (size_t)128 * KK;
  char* const sA = smem;
  char* const sB = smem + 65536;
  const int woff = w * 1024;    // wave-uniform dest base within region

  // ---- read addressing (swizzled ds_read) ----
  const int m16 = lane & 15;
  const int q = lane >> 4;                    // K-quad (8 bf16)
  const int rsw = (q ^ ((m16 >> 1) & 3)) * 16;
  const int aoff = (wm * 128 + m16) * 64 + rsw;   // + i*1024 per m-frag
  const int boff = (wn * 64 + m16) * 64 + rsw;    // + j*1024 per n-frag

  floatx4 acc[8][4];
#pragma unroll
  for (int i = 0; i < 8; i++)
#pragma unroll
    for (int j = 0; j < 4; j++) acc[i][j] = (floatx4){0.f, 0.f, 0.f, 0.f};

  bf16x8 bfrag[4];  // B frags persist across the two m-half phases of a K-half

#define STAGE_A(kt_, par_, kh_)                                          \
  do {                                                                   \
    const int ko_ = (kt_) * GBK + (kh_) * 32;                            \
    char* d_ = sA + ((par_) * 32768 + (kh_) * 16384) + woff;             \
    async_ld16(gA1 + ko_, d_);                                           \
    async_ld16(gA2 + ko_, d_ + 8192);                                    \
  } while (0)
#define STAGE_B(kt_, par_, kh_)                                          \
  do {                                                                   \
    const int ko_ = (kt_) * GBK + (kh_) * 32;                            \
    char* d_ = sB + ((par_) * 32768 + (kh_) * 16384) + woff;             \
    async_ld16(gB1 + ko_, d_);                                           \
    async_ld16(gB2 + ko_, d_ + 8192);                                    \
  } while (0)

#define VM6 asm volatile("s_waitcnt vmcnt(6)" ::: "memory")
#define VM0 asm volatile("s_waitcnt vmcnt(0)" ::: "memory")

#define PHASE(p_, kh_, mh_, STAGES, VMW)                                          \
  do {                                                                            \
    const char* ab_ = sA + ((p_) * 32768 + (kh_) * 16384) + aoff;                 \
    bf16x8 af_[4];                                                                \
    _Pragma("unroll") for (int i_ = 0; i_ < 4; i_++)                              \
        af_[i_] = *(const bf16x8*)(ab_ + ((mh_) * 4 + i_) * 1024);                \
    if ((mh_) == 0) {                                                             \
      const char* bb_ = sB + ((p_) * 32768 + (kh_) * 16384) + boff;               \
      _Pragma("unroll") for (int j_ = 0; j_ < 4; j_++)                            \
          bfrag[j_] = *(const bf16x8*)(bb_ + j_ * 1024);                          \
    }                                                                             \
    STAGES;                                                                       \
    __builtin_amdgcn_sched_barrier(0);                                            \
    __builtin_amdgcn_s_barrier();                                                 \
    __builtin_amdgcn_sched_barrier(0);                                            \
    asm volatile("s_waitcnt lgkmcnt(0)" ::: "memory");                            \
    __builtin_amdgcn_sched_barrier(0);                                            \
    __builtin_amdgcn_s_setprio(1);                                                \
    _Pragma("unroll") for (int i_ = 0; i_ < 4; i_++) {                            \
      _Pragma("unroll") for (int j_ = 0; j_ < 4; j_++) {                          \
        acc[(mh_) * 4 + i_][j_] = __builtin_amdgcn_mfma_f32_16x16x32_bf16(        \
            af_[i_], bfrag[j_], acc[(mh_) * 4 + i_][j_], 0, 0, 0);                \
      }                                                                           \
    }                                                                             \
    __builtin_amdgcn_s_setprio(0);                                                \
    VMW;                                                                          \
    __builtin_amdgcn_sched_barrier(0);                                            \
    __builtin_amdgcn_s_barrier();                                                 \
    __builtin_amdgcn_sched_barrier(0);                                            \
  } while (0)

  // ---- prologue ----
  STAGE_A(0, 0, 0); STAGE_B(0, 0, 0); STAGE_A(0, 0, 1); STAGE_B(0, 0, 1);
  STAGE_B(1, 1, 0); STAGE_A(1, 1, 0); STAGE_B(1, 1, 1);
  VM6;
  __builtin_amdgcn_s_barrier();

  // ---- main loop ----
  for (int it = 0; it < 7; ++it) {
    const int kt0 = 2 * it;
    const int kt1 = 2 * it + 1;
    PHASE(0, 0, 0, STAGE_A(kt0 + 1, 1, 1), );
    PHASE(0, 0, 1, STAGE_B(kt0 + 2, 0, 0), );
    PHASE(0, 1, 0, STAGE_A(kt0 + 2, 0, 0), );
    PHASE(0, 1, 1, STAGE_B(kt0 + 2, 0, 1), VM6);
    PHASE(1, 0, 0, STAGE_A(kt1 + 1, 0, 1), );
    PHASE(1, 0, 1, STAGE_B(kt1 + 2, 1, 0), );
    PHASE(1, 1, 0, STAGE_A(kt1 + 2, 1, 0), );
    PHASE(1, 1, 1, STAGE_B(kt1 + 2, 1, 1), VM6);
  }

  // ---- tail ----
  PHASE(0, 0, 0, STAGE_A(15, 1, 1), );
  PHASE(0, 0, 1, , );
  PHASE(0, 1, 0, , );
  PHASE(0, 1, 1, , VM0);
  PHASE(1, 0, 0, , );
  PHASE(1, 0, 1, , );
  PHASE(1, 1, 0, , );
  PHASE(1, 1, 1, , );

#undef PHASE
#undef STAGE_A
#undef STAGE_B
#undef VM6
#undef VM0

  // ---- epilogue: LDS-staged, coalesced 64B-sector stores ----
  const int mode = bn >> 2;  // 0: x_tilde, 1: f, 2: r
  ushort_t* const eps = (ushort_t*)smem;
  const int EPS = 264;  // ushorts per staged row (528 B): 2-way bank spread
  float bias_r[4];
#pragma unroll
  for (int j = 0; j < 4; j++) bias_r[j] = bias[rowB0 + wn * 64 + j * 16 + m16];

  const int erow = tid >> 2;        // 0..127 read-out row
  const int et3 = tid & 3;          // 16B sub-slot
#pragma unroll
  for (int mh = 0; mh < 2; mh++) {
    __syncthreads();
    if (wm == mh) {
#pragma unroll
      for (int i = 0; i < 8; i++) {
#pragma unroll
        for (int j = 0; j < 4; j++) {
          const int lc = wn * 64 + j * 16 + m16;
#pragma unroll
          for (int r = 0; r < 4; r++) {
            float v = acc[i][j][r] + bias_r[j];
            if (mode != 0) v = fast_sigmoid(v);
            const int lr = i * 16 + q * 4 + r;  // 0..127
            eps[lr * EPS + lc] = f2b(v);
          }
        }
      }
    }
    __syncthreads();
    ushort_t* gout = U + (size_t)(rowA0 + mh * 128 + erow) * NN + rowB0;
#pragma unroll
    for (int k = 0; k < 8; k++) {
      *(uint4*)(gout + k * 32 + et3 * 8) =
          *(const uint4*)(eps + erow * EPS + k * 32 + et3 * 8);
    }
  }
}

// ---------- kernel 3: per-chunk scan summaries, 16B/lane + 4 blocks/CU ----------
__global__ __launch_bounds__(256) void pass1_kernel(const ushort_t* __restrict__ U,
                                                    float* __restrict__ Asum,
                                                    float* __restrict__ Bsum) {
  int gid = blockIdx.x * 256 + threadIdx.x;  // 262144
  int hp = gid & 127;            // 8-col group
  int chunk = (gid >> 7) & 127;  // 0..127
  int b = gid >> 14;
  int row0 = b * TT + chunk * CLEN;
  const ushort_t* base = U + (size_t)row0 * NN + hp * 8;
  float c[8], A[8];
#pragma unroll
  for (int e = 0; e < 8; e++) { c[e] = 0.f; A[e] = 1.f; }
#pragma unroll 4
  for (int t = 0; t < CLEN; t++) {
    const ushort_t* p = base + (size_t)t * NN;
    uint4 xx = *(const uint4*)(p);
    uint4 ff = *(const uint4*)(p + HH);
    float xv[8], fv[8];
    xv[0] = b2f_lo(xx.x); xv[1] = b2f_hi(xx.x);
    xv[2] = b2f_lo(xx.y); xv[3] = b2f_hi(xx.y);
    xv[4] = b2f_lo(xx.z); xv[5] = b2f_hi(xx.z);
    xv[6] = b2f_lo(xx.w); xv[7] = b2f_hi(xx.w);
    fv[0] = b2f_lo(ff.x); fv[1] = b2f_hi(ff.x);
    fv[2] = b2f_lo(ff.y); fv[3] = b2f_hi(ff.y);
    fv[4] = b2f_lo(ff.z); fv[5] = b2f_hi(ff.z);
    fv[6] = b2f_lo(ff.w); fv[7] = b2f_hi(ff.w);
#pragma unroll
    for (int e = 0; e < 8; e++) {
      A[e] *= fv[e];
      c[e] = fv[e] * c[e] + (1.f - fv[e]) * xv[e];
    }
  }
  int sidx = (b * NCHUNK + chunk) * HH + hp * 8;
  float4* A4 = (float4*)(Asum + sidx);
  float4* B4 = (float4*)(Bsum + sidx);
  A4[0] = make_float4(A[0], A[1], A[2], A[3]);
  A4[1] = make_float4(A[4], A[5], A[6], A[7]);
  B4[0] = make_float4(c[0], c[1], c[2], c[3]);
  B4[1] = make_float4(c[4], c[5], c[6], c[7]);
}

// ---------- kernel 4: sequential combine over chunk summaries (float4) ----------
__global__ __launch_bounds__(256) void fixup_kernel(const float4* __restrict__ Asum,
                                                    const float4* __restrict__ Bsum,
                                                    float4* __restrict__ Cinit) {
  int gid = blockIdx.x * 256 + threadIdx.x;  // 4096
  int h4 = gid & 255;   // float4 index within 1024 cols
  int b = gid >> 8;
  float4 c = make_float4(0.f, 0.f, 0.f, 0.f);
#pragma unroll 8
  for (int j = 0; j < NCHUNK; j++) {
    int idx = (b * NCHUNK + j) * (HH / 4) + h4;
    Cinit[idx] = c;
    float4 a = Asum[idx], bb = Bsum[idx];
    c.x = bb.x + a.x * c.x;
    c.y = bb.y + a.y * c.y;
    c.z = bb.z + a.z * c.z;
    c.w = bb.w + a.w * c.w;
  }
}

// ---------- kernel 5: final scan producing h, 16B/lane + 4 blocks/CU ----------
__global__ __launch_bounds__(256) void pass3_kernel(const ushort_t* __restrict__ U,
                                                    const float* __restrict__ Cinit,
                                                    float* __restrict__ out) {
  int gid = blockIdx.x * 256 + threadIdx.x;  // 262144
  int hp = gid & 127;
  int chunk = (gid >> 7) & 127;
  int b = gid >> 14;
  int row0 = b * TT + chunk * CLEN;
  const ushort_t* base = U + (size_t)row0 * NN + hp * 8;
  int ci = (b * NCHUNK + chunk) * HH + hp * 8;
  float c[8];
  {
    float4 c0 = *(const float4*)(Cinit + ci);
    float4 c1 = *(const float4*)(Cinit + ci + 4);
    c[0] = c0.x; c[1] = c0.y; c[2] = c0.z; c[3] = c0.w;
    c[4] = c1.x; c[5] = c1.y; c[6] = c1.z; c[7] = c1.w;
  }
  float* obase = out + (size_t)row0 * HH + hp * 8;
#pragma unroll 2
  for (int t = 0; t < CLEN; t++) {
    const ushort_t* p = base + (size_t)t * NN;
    uint4 xx = *(const uint4*)(p);
    uint4 ff = *(const uint4*)(p + HH);
    uint4 rr = *(const uint4*)(p + 2 * HH);
    float xv[8], fv[8], rv[8];
    xv[0] = b2f_lo(xx.x); xv[1] = b2f_hi(xx.x);
    xv[2] = b2f_lo(xx.y); xv[3] = b2f_hi(xx.y);
    xv[4] = b2f_lo(xx.z); xv[5] = b2f_hi(xx.z);
    xv[6] = b2f_lo(xx.w); xv[7] = b2f_hi(xx.w);
    fv[0] = b2f_lo(ff.x); fv[1] = b2f_hi(ff.x);
    fv[2] = b2f_lo(ff.y); fv[3] = b2f_hi(ff.y);
    fv[4] = b2f_lo(ff.z); fv[5] = b2f_hi(ff.z);
    fv[6] = b2f_lo(ff.w); fv[7] = b2f_hi(ff.w);
    rv[0] = b2f_lo(rr.x); rv[1] = b2f_hi(rr.x);
    rv[2] = b2f_lo(rr.y); rv[3] = b2f_hi(rr.y);
    rv[4] = b2f_lo(rr.z); rv[5] = b2f_hi(rr.z);
    rv[6] = b2f_lo(rr.w); rv[7] = b2f_hi(rr.w);
    float h[8];
#pragma unroll
    for (int e = 0; e < 8; e++) {
      c[e] = fv[e] * c[e] + (1.f - fv[e]) * xv[e];
      h[e] = rv[e] * fast_tanh(c[e]) + (1.f - rv[e]) * xv[e];
    }
    float* o = obase + (size_t)t * HH;
    ((float4*)o)[0] = make_float4(h[0], h[1], h[2], h[3]);
    ((float4*)o)[1] = make_float4(h[4], h[5], h[6], h[7]);
  }
}

extern "C" void kernel_launch(void* const* d_in, const int* in_sizes, int n_in,
                              void* d_out, int out_size, void* d_ws, size_t ws_size,
                              hipStream_t stream) {
  (void)in_sizes; (void)n_in; (void)out_size; (void)ws_size;
  const float* x = (const float*)d_in[0];
  const float* W = (const float*)d_in[1];
  const float* bias = (const float*)d_in[2];
  float* out = (float*)d_out;
  char* ws = (char*)d_ws;

  // workspace layout (~275 MB).
  // Asum/Bsum/Cinit (8 MB each) OVERLAP x_bf (dead after gemm8; stream-ordered).
  ushort_t* x_bf = (ushort_t*)ws;                                     // 67,108,864 B
  ushort_t* Wt   = (ushort_t*)(ws + 67108864ull);                     //  6,291,456 B
  ushort_t* U    = (ushort_t*)(ws + 67108864ull + 6291456ull);        // 201,326,592 B
  float* Asum  = (float*)ws;                                          //  8,388,608 B
  float* Bsum  = (float*)(ws + 8388608ull);                           //  8,388,608 B
  float* Cinit = (float*)(ws + 16777216ull);                          //  8,388,608 B

  static int gemm_attr_set = 0;
  if (!gemm_attr_set) {
    (void)hipFuncSetAttribute(reinterpret_cast<const void*>(gemm8_kernel),
                              hipFuncAttributeMaxDynamicSharedMemorySize, 131072);
    gemm_attr_set = 1;
  }

  prep_kernel<<<7168, 256, 0, stream>>>((const floatx4*)x, (uintx4*)x_bf, W, Wt);
  gemm8_kernel<<<NWG, 512, 131072, stream>>>(x_bf, Wt, bias, U);
  pass1_kernel<<<1024, 256, 0, stream>>>(U, Asum, Bsum);
  fixup_kernel<<<16, 256, 0, stream>>>((const float4*)Asum, (const float4*)Bsum,
                                       (float4*)Cinit);
  pass3_kernel<<<1024, 256, 0, stream>>>(U, Cinit, out);
}